// Round 4
// baseline (1697.256 us; speedup 1.0000x reference)
//
#include <hip/hip_runtime.h>
#include <math.h>

#define B 16
#define C 384
#define H 96
#define W 96
#define HW (H*W)
#define M 2048
#define K2 49
#define RAD 3
#define NSEL 512
#define INV_TAU 10.0f
#define TSP 64           // pixels per transpose block
#define CCH 96           // channels per transpose chunk

__device__ inline float wave_max(float v){
  #pragma unroll
  for (int o = 32; o; o >>= 1) v = fmaxf(v, __shfl_xor(v, o));
  return v;
}
__device__ inline float wave_sum(float v){
  #pragma unroll
  for (int o = 32; o; o >>= 1) v += __shfl_xor(v, o);
  return v;
}

// ---------------- patch-similarity core ----------------
// 16 lanes per neighbor, 4 neighbors per pass, 14 passes (7 rows x 2).
// Software-pipelined double buffer with sched_barrier fences (round-2 lesson:
// without fences + VGPR budget the compiler serializes the load batch).
__device__ __forceinline__ float patch_sims(const float* __restrict__ img,
                                            int ay, int ax, int lane){
  int g = lane >> 4, t = lane & 15;
  const float2* cp = (const float2*)(img + (size_t)(ay * W + ax) * C) + t;
  float2 c[12];
  #pragma unroll
  for (int j = 0; j < 12; ++j) c[j] = cp[16 * j];
  float mysim = 0.f;
  float2 bA[12], bB[12];

#define PLOAD(buf, pp) { \
    int dxl = ((pp) & 1) * 4 + g; if (dxl > 6) dxl = 6; \
    const float2* np = (const float2*)(img + \
        (size_t)((ay + ((pp) >> 1) - RAD) * W + (ax - RAD + dxl)) * C) + t; \
    _Pragma("unroll") for (int j = 0; j < 12; ++j) buf[j] = np[16 * j]; }

#define PCOMP(buf, pp) { \
    float a0 = 0.f, a1 = 0.f; \
    _Pragma("unroll") for (int j = 0; j < 6; ++j){ \
      a0 = fmaf(c[j].x, buf[j].x, a0); a0 = fmaf(c[j].y, buf[j].y, a0); \
      a1 = fmaf(c[j+6].x, buf[j+6].x, a1); a1 = fmaf(c[j+6].y, buf[j+6].y, a1); } \
    float a = a0 + a1; \
    a += __shfl_xor(a, 8); a += __shfl_xor(a, 4); \
    a += __shfl_xor(a, 2); a += __shfl_xor(a, 1); \
    int kbase = ((pp) >> 1) * 7 + ((pp) & 1) * 4; \
    int npass = ((pp) & 1) ? 3 : 4; \
    float v = __shfl(a, ((lane - kbase) & 3) << 4); \
    if (lane >= kbase && lane < kbase + npass) mysim = v; }

  PLOAD(bA, 0);
  #pragma unroll
  for (int pp = 0; pp < 14; pp += 2){
    PLOAD(bB, pp + 1);
    __builtin_amdgcn_sched_barrier(0);
    PCOMP(bA, pp);
    if (pp + 2 < 14) PLOAD(bA, pp + 2);
    __builtin_amdgcn_sched_barrier(0);
    PCOMP(bB, pp + 1);
  }
#undef PLOAD
#undef PCOMP
  return mysim;
}

// ---------------- fast path: pixel-major layout ----------------

// Streaming inverse norms for BOTH tensors. Summation replicates the old
// tnorm order exactly (8 sequential-48 partials combined in a binary tree)
// so scales are bitwise identical to previous rounds.
__global__ void norms2_kernel(const float* __restrict__ t, const float* __restrict__ s,
                              float* __restrict__ inv_t, float* __restrict__ inv_s){
  int pix = blockIdx.x * 256 + threadIdx.x;    // B*HW threads
  int b = pix / HW, p = pix - b * HW;
  const float* tb = t + (size_t)b * C * HW + p;
  const float* sb = s + (size_t)b * C * HW + p;
  float pt[8], ps[8];
  #pragma unroll
  for (int k = 0; k < 8; ++k){
    float at = 0.f, as = 0.f;
    #pragma unroll 4
    for (int c = k * 48; c < k * 48 + 48; ++c){
      float v = tb[(size_t)c * HW]; at = fmaf(v, v, at);
      float u = sb[(size_t)c * HW]; as = fmaf(u, u, as);
    }
    pt[k] = at; ps[k] = as;
  }
  // tree: ((p0+p1)+(p2+p3)) + ((p4+p5)+(p6+p7)) — matches old shfl_xor 1,2,4
  float at = ((pt[0]+pt[1]) + (pt[2]+pt[3])) + ((pt[4]+pt[5]) + (pt[6]+pt[7]));
  float as = ((ps[0]+ps[1]) + (ps[2]+ps[3])) + ((ps[4]+ps[5]) + (ps[6]+ps[7]));
  inv_t[pix] = 1.0f / fmaxf(sqrtf(at), 1e-12f);
  inv_s[pix] = 1.0f / fmaxf(sqrtf(as), 1e-12f);
}

// Chunked transpose+scale: [C, HW] -> [pix, C], scale applied at load.
// LDS 64x97x4 = 24.8 KB -> 6 blocks/CU (old tnorm: 49 KB -> 3 blocks/CU).
// No cross-thread reduction, loads 256B-contiguous per instruction.
__global__ __launch_bounds__(256) void tscale_kernel(const float* __restrict__ src,
                              const float* __restrict__ inv, float* __restrict__ dst){
  int blk = blockIdx.x;                 // B * (HW/TSP)
  int b = blk / (HW / TSP);
  int pixbase = (blk % (HW / TSP)) * TSP;
  __shared__ float tile[TSP][CCH + 1];
  int tx = threadIdx.x & 63;            // pixel
  int ty = threadIdx.x >> 6;            // 0..3
  const float* sb = src + (size_t)b * C * HW + pixbase + tx;
  float sc = inv[b * HW + pixbase + tx];
  float* db = dst + ((size_t)b * HW + pixbase) * C;
  #pragma unroll
  for (int ch = 0; ch < C / CCH; ++ch){
    #pragma unroll
    for (int cc = 0; cc < CCH; cc += 4){
      tile[tx][cc + ty] = sb[(size_t)(ch * CCH + cc + ty) * HW] * sc;
    }
    __syncthreads();
    #pragma unroll
    for (int j = 0; j < 6; ++j){
      int idx = threadIdx.x + 256 * j;  // 0..1535 over 64 pix x 24 float4
      int pix = idx / 24, c4 = idx - pix * 24;
      float4 v;
      v.x = tile[pix][c4 * 4 + 0];
      v.y = tile[pix][c4 * 4 + 1];
      v.z = tile[pix][c4 * 4 + 2];
      v.w = tile[pix][c4 * 4 + 3];
      ((float4*)(db + (size_t)pix * C + ch * CCH))[c4] = v;
    }
    __syncthreads();
  }
}

// Spatial sort of the (image-shared) candidate list by 8x8 tile, ties by idx.
__global__ void sort_kernel(const int* __restrict__ anch, int* __restrict__ order){
  int i = blockIdx.x * 256 + threadIdx.x;    // 8 blocks x 256
  __shared__ int keys[M];
  for (int j = threadIdx.x; j < M; j += 256){
    int ay = anch[2 * j], ax = anch[2 * j + 1];
    keys[j] = (((ay >> 3) * 12 + (ax >> 3)) << 11) + j;
  }
  __syncthreads();
  int ki = keys[i];
  int r = 0;
  #pragma unroll 4
  for (int j = 0; j < M; ++j) r += (keys[j] < ki) ? 1 : 0;
  order[r] = i;
}

// 4 waves per block; one wave per (b, candidate). (256,8): VGPR demand is 64
// (measured) -> 8 blocks/CU fits; round-3's (256,4) capped occupancy at 50%.
__global__ __launch_bounds__(256, 8) void cand2_kernel(const float* __restrict__ fT,
                             const int* __restrict__ anch, const int* __restrict__ order,
                             float* __restrict__ simc, float* __restrict__ ent){
  int nwg = B * M / 4;
  int bid = blockIdx.x;
  int swz = (bid & 7) * (nwg >> 3) + (bid >> 3);   // bijective, nwg%8==0
  int bm = swz * 4 + (threadIdx.x >> 6);
  int b = bm >> 11, mi = bm & (M - 1);
  int lane = threadIdx.x & 63;
  int m = order ? order[mi] : mi;
  int ay = anch[2 * m], ax = anch[2 * m + 1];
  const float* img = fT + (size_t)b * HW * C;
  float mysim = patch_sims(img, ay, ax, lane) * INV_TAU;

  float v = (lane < K2) ? mysim : -INFINITY;
  float mx = wave_max(v);
  float e = (lane < K2) ? expf(mysim - mx) : 0.f;
  float se = wave_sum(e);
  float p = e / se;
  float term = (lane < K2) ? (-p * logf(p + 1e-6f)) : 0.f;
  float en = wave_sum(term);
  size_t slot = (size_t)b * M + m;
  if (lane == 0) ent[slot] = en;
  if (lane < K2) simc[slot * K2 + lane] = mysim;
}

// Exact top-512-smallest-entropy per image via lexicographic rank counting.
__global__ void select_kernel(const float* __restrict__ ent, int* __restrict__ sel){
  int blk = blockIdx.x;                 // B*8 blocks
  int b = blk >> 3;
  int i = (blk & 7) * 256 + threadIdx.x;
  __shared__ float se[M];
  for (int j = threadIdx.x; j < M; j += 256) se[j] = ent[b * M + j];
  __syncthreads();
  float ei = se[i];
  int r = 0;
  for (int j = 0; j < M; ++j){
    float ej = se[j];
    r += (ej < ei) || (ej == ei && j < i);
  }
  if (r < NSEL) sel[b * NSEL + r] = i;
}

// Spatially sort each image's 512 selected anchors for kl2 L2 locality.
// Packs (orig_pos << 11 | m): klpart slots keyed by orig_pos -> final sum
// order (and output bits) unchanged.
__global__ void selsort_kernel(const int* __restrict__ anch, const int* __restrict__ sel,
                               int* __restrict__ sel2){
  int b = blockIdx.x;                   // B blocks
  __shared__ int keys[NSEL];
  __shared__ int pos[NSEL];
  for (int j = threadIdx.x; j < NSEL; j += 256){
    int m = sel[b * NSEL + j];
    int ay = anch[2 * m], ax = anch[2 * m + 1];
    keys[j] = (((ay >> 3) * 12 + (ax >> 3)) << 11) | m;   // unique (m unique)
    pos[j] = j;
  }
  __syncthreads();
  for (int j = threadIdx.x; j < NSEL; j += 256){
    int kj = keys[j];
    int r = 0;
    #pragma unroll 4
    for (int i = 0; i < NSEL; ++i) r += (keys[i] < kj) ? 1 : 0;
    sel2[b * NSEL + r] = (pos[j] << 11) | (kj & (M - 1));
  }
}

// 4 waves per block; one wave per (b, sorted-selected anchor).
__global__ __launch_bounds__(256, 8) void kl2_kernel(const float* __restrict__ fS,
                           const int* __restrict__ anch,
                           const float* __restrict__ simc, const int* __restrict__ sel2,
                           float* __restrict__ klpart){
  int nwg = B * NSEL / 4;
  int bid = blockIdx.x;
  int swz = (bid & 7) * (nwg >> 3) + (bid >> 3);
  int bj = swz * 4 + (threadIdx.x >> 6);
  int b = bj >> 9, j = bj & (NSEL - 1);
  int lane = threadIdx.x & 63;
  int e2 = sel2[b * NSEL + j];
  int m = e2 & (M - 1), pos = e2 >> 11;
  int ay = anch[2 * m], ax = anch[2 * m + 1];
  const float* img = fS + (size_t)b * HW * C;
  float sim_sv = patch_sims(img, ay, ax, lane) * INV_TAU;
  float sim_tv = (lane < K2) ? simc[((size_t)b * M + m) * K2 + lane] : -INFINITY;

  float vs = (lane < K2) ? sim_sv : -INFINITY;
  float mxs = wave_max(vs);
  float es = (lane < K2) ? expf(sim_sv - mxs) : 0.f;
  float sums = wave_sum(es);
  float ls = sim_sv - mxs - logf(sums);

  float mxt = wave_max(sim_tv);
  float et = (lane < K2) ? expf(sim_tv - mxt) : 0.f;
  float sumt = wave_sum(et);
  float lt = sim_tv - mxt - logf(sumt);

  float pt = et / sumt;
  float term = (lane < K2) ? pt * (lt - ls) : 0.f;
  float kl = wave_sum(term);
  if (lane == 0) klpart[(b << 9) + pos] = kl;
}

__global__ void reduce_kernel(const float* __restrict__ part, float* __restrict__ out){
  float s = 0.f;
  for (int i = threadIdx.x; i < B * NSEL; i += 256) s += part[i];
  s = wave_sum(s);
  __shared__ float wsum[4];
  if ((threadIdx.x & 63) == 0) wsum[threadIdx.x >> 6] = s;
  __syncthreads();
  if (threadIdx.x == 0) out[0] = (wsum[0] + wsum[1] + wsum[2] + wsum[3]) * (1.0f / (B * NSEL));
}

// ---------------- fallback path (round-1, ~13 MB ws) ----------------

__global__ void norms_kernel(const float* __restrict__ t, const float* __restrict__ s,
                             float* __restrict__ inv_t, float* __restrict__ inv_s){
  int pix = blockIdx.x * blockDim.x + threadIdx.x;
  if (pix >= B * HW) return;
  int b = pix / HW, p = pix - b * HW;
  const float* tb = t + (size_t)b * C * HW + p;
  const float* sb = s + (size_t)b * C * HW + p;
  float at = 0.f, as = 0.f;
  #pragma unroll 4
  for (int c = 0; c < C; ++c){
    float v = tb[(size_t)c * HW]; at = fmaf(v, v, at);
    float u = sb[(size_t)c * HW]; as = fmaf(u, u, as);
  }
  inv_t[pix] = 1.0f / fmaxf(sqrtf(at), 1e-12f);
  inv_s[pix] = 1.0f / fmaxf(sqrtf(as), 1e-12f);
}

__global__ void cand_kernel(const float* __restrict__ t, const int* __restrict__ anch,
                            const float* __restrict__ inv_t,
                            float* __restrict__ simc, float* __restrict__ ent){
  int bm = blockIdx.x;
  int b = bm >> 11, m = bm & (M - 1);
  int lane = threadIdx.x;
  int ay = anch[2 * m], ax = anch[2 * m + 1];
  int k = lane < K2 ? lane : 0;
  int dy = k / 7 - RAD, dx = k - (k / 7) * 7 - RAD;
  int pc = ay * W + ax;
  int pk = (ay + dy) * W + (ax + dx);
  const float* base = t + (size_t)b * C * HW;
  float acc = 0.f;
  #pragma unroll 4
  for (int c = 0; c < C; ++c){
    const float* row = base + (size_t)c * HW;
    acc = fmaf(row[pc], row[pk], acc);
  }
  float sim = acc * inv_t[b * HW + pc] * inv_t[b * HW + pk] * INV_TAU;
  float v = (lane < K2) ? sim : -INFINITY;
  float mx = wave_max(v);
  float e = (lane < K2) ? expf(sim - mx) : 0.f;
  float se = wave_sum(e);
  float p = e / se;
  float term = (lane < K2) ? (-p * logf(p + 1e-6f)) : 0.f;
  float en = wave_sum(term);
  if (lane == 0) ent[bm] = en;
  if (lane < K2) simc[(size_t)bm * K2 + lane] = sim;
}

__global__ void kl_kernel(const float* __restrict__ s, const int* __restrict__ anch,
                          const float* __restrict__ inv_s, const float* __restrict__ simc,
                          const int* __restrict__ sel, float* __restrict__ klpart){
  int bj = blockIdx.x;
  int b = bj >> 9, j = bj & (NSEL - 1);
  int lane = threadIdx.x;
  int m = sel[b * NSEL + j];
  int ay = anch[2 * m], ax = anch[2 * m + 1];
  int k = lane < K2 ? lane : 0;
  int dy = k / 7 - RAD, dx = k - (k / 7) * 7 - RAD;
  int pc = ay * W + ax;
  int pk = (ay + dy) * W + (ax + dx);
  const float* base = s + (size_t)b * C * HW;
  float acc = 0.f;
  #pragma unroll 4
  for (int c = 0; c < C; ++c){
    const float* row = base + (size_t)c * HW;
    acc = fmaf(row[pc], row[pk], acc);
  }
  float sim_sv = acc * inv_s[b * HW + pc] * inv_s[b * HW + pk] * INV_TAU;
  float sim_tv = (lane < K2) ? simc[((size_t)b * M + m) * K2 + lane] : -INFINITY;

  float vs = (lane < K2) ? sim_sv : -INFINITY;
  float mxs = wave_max(vs);
  float es = (lane < K2) ? expf(sim_sv - mxs) : 0.f;
  float sums = wave_sum(es);
  float ls = sim_sv - mxs - logf(sums);

  float mxt = wave_max(sim_tv);
  float et = (lane < K2) ? expf(sim_tv - mxt) : 0.f;
  float sumt = wave_sum(et);
  float lt = sim_tv - mxt - logf(sumt);

  float pt = et / sumt;
  float term = (lane < K2) ? pt * (lt - ls) : 0.f;
  float kl = wave_sum(term);
  if (lane == 0) klpart[bj] = kl;
}

extern "C" void kernel_launch(void* const* d_in, const int* in_sizes, int n_in,
                              void* d_out, int out_size, void* d_ws, size_t ws_size,
                              hipStream_t stream){
  const float* student = (const float*)d_in[0];
  const float* teacher = (const float*)d_in[1];
  const int*   anch    = (const int*)d_in[2];
  float* out = (float*)d_out;

  const size_t fbuf_elems = (size_t)B * HW * C;            // 56.6M floats
  const size_t simc_elems = (size_t)B * M * K2;
  const size_t inv_elems  = (size_t)B * HW;
  size_t req = (fbuf_elems + simc_elems + 2 * inv_elems + (size_t)B * M + (size_t)B * NSEL) * sizeof(float)
             + (2 * (size_t)B * NSEL + (size_t)M) * sizeof(int);

  if (ws_size >= req){
    float* fbuf   = (float*)d_ws;                          // reused: teacher then student
    float* simc   = fbuf + fbuf_elems;
    float* inv_t  = simc + simc_elems;
    float* inv_s  = inv_t + inv_elems;
    float* ent    = inv_s + inv_elems;
    float* klpart = ent + (size_t)B * M;
    int*   sel    = (int*)(klpart + (size_t)B * NSEL);
    int*   sel2   = sel + (size_t)B * NSEL;
    int*   order  = sel2 + (size_t)B * NSEL;

    hipLaunchKernelGGL(norms2_kernel, dim3(B * HW / 256), dim3(256), 0, stream,
                       teacher, student, inv_t, inv_s);
    hipLaunchKernelGGL(sort_kernel, dim3(8), dim3(256), 0, stream, anch, order);
    hipLaunchKernelGGL(tscale_kernel, dim3(B * (HW / TSP)), dim3(256), 0, stream,
                       teacher, inv_t, fbuf);
    hipLaunchKernelGGL(cand2_kernel, dim3(B * M / 4), dim3(256), 0, stream,
                       fbuf, anch, order, simc, ent);
    hipLaunchKernelGGL(select_kernel, dim3(B * 8), dim3(256), 0, stream, ent, sel);
    hipLaunchKernelGGL(selsort_kernel, dim3(B), dim3(256), 0, stream, anch, sel, sel2);
    hipLaunchKernelGGL(tscale_kernel, dim3(B * (HW / TSP)), dim3(256), 0, stream,
                       student, inv_s, fbuf);
    hipLaunchKernelGGL(kl2_kernel, dim3(B * NSEL / 4), dim3(256), 0, stream,
                       fbuf, anch, simc, sel2, klpart);
    hipLaunchKernelGGL(reduce_kernel, dim3(1), dim3(256), 0, stream, klpart, out);
  } else {
    float* ws2    = (float*)d_ws;
    float* inv_t  = ws2;
    float* inv_s  = inv_t + B * HW;
    float* ent    = inv_s + B * HW;
    float* simc   = ent + B * M;
    float* klpart = simc + simc_elems;
    int*   sel    = (int*)(klpart + (size_t)B * NSEL);

    hipLaunchKernelGGL(norms_kernel, dim3((B * HW + 255) / 256), dim3(256), 0, stream,
                       teacher, student, inv_t, inv_s);
    hipLaunchKernelGGL(cand_kernel, dim3(B * M), dim3(64), 0, stream,
                       teacher, anch, inv_t, simc, ent);
    hipLaunchKernelGGL(select_kernel, dim3(B * 8), dim3(256), 0, stream, ent, sel);
    hipLaunchKernelGGL(kl_kernel, dim3(B * NSEL), dim3(64), 0, stream,
                       student, anch, inv_s, simc, sel, klpart);
    hipLaunchKernelGGL(reduce_kernel, dim3(1), dim3(256), 0, stream, klpart, out);
  }
}

// Round 5
// 903.734 us; speedup vs baseline: 1.8780x; 1.8780x over previous
//
#include <hip/hip_runtime.h>
#include <math.h>

#define B 16
#define C 384
#define CPAD 385
#define H 96
#define W 96
#define HW (H*W)
#define M 2048
#define K2 49
#define RAD 3
#define NSEL 512
#define INV_TAU 10.0f
#define TP 32            // pixels per transpose tile

__device__ inline float wave_max(float v){
  #pragma unroll
  for (int o = 32; o; o >>= 1) v = fmaxf(v, __shfl_xor(v, o));
  return v;
}
__device__ inline float wave_sum(float v){
  #pragma unroll
  for (int o = 32; o; o >>= 1) v += __shfl_xor(v, o);
  return v;
}

// ---------------- patch-similarity core (round 5) ----------------
// 32 lanes per neighbor, 2 neighbors per pass, 28 passes (7 rows x 4).
// float4 loads: 3 per lane, 512B contiguous per instruction (vs 12 float2).
// Register demand ~52 (c:12 + bufA:12 + bufB:12 + addr/misc) — fits the
// 64-VGPR/8-blocks-per-CU occupancy tier. Round-4 lesson: (256,8) budget 64
// < demand 64+granule -> spill catastrophe; here demand is cut instead.
// Double buffer + sched_barrier fences (round-2 lesson: else compiler
// serializes the load batch).
__device__ __forceinline__ float patch_sims(const float* __restrict__ img,
                                            int ay, int ax, int lane){
  int g = lane >> 5, t = lane & 31;
  const float4* cp = (const float4*)(img + (size_t)(ay * W + ax) * C) + t;
  float4 c0 = cp[0], c1 = cp[32], c2 = cp[64];
  float mysim = 0.f;
  float4 a0, a1, a2, b0, b1, b2;

#define PLOAD(p0,p1,p2, pp) { \
    int dxl = ((pp) & 3) * 2 + g; if (dxl > 6) dxl = 6; \
    const float4* np = (const float4*)(img + \
        (size_t)((ay + ((pp) >> 2) - RAD) * W + (ax - RAD + dxl)) * C) + t; \
    p0 = np[0]; p1 = np[32]; p2 = np[64]; }

#define PCOMP(p0,p1,p2, pp) { \
    float s0 = c0.x * p0.x; s0 = fmaf(c0.y, p0.y, s0); \
    s0 = fmaf(c0.z, p0.z, s0); s0 = fmaf(c0.w, p0.w, s0); \
    float s1 = c1.x * p1.x; s1 = fmaf(c1.y, p1.y, s1); \
    s1 = fmaf(c1.z, p1.z, s1); s1 = fmaf(c1.w, p1.w, s1); \
    float s2 = c2.x * p2.x; s2 = fmaf(c2.y, p2.y, s2); \
    s2 = fmaf(c2.z, p2.z, s2); s2 = fmaf(c2.w, p2.w, s2); \
    float a = (s0 + s1) + s2; \
    a += __shfl_xor(a, 16); a += __shfl_xor(a, 8); \
    a += __shfl_xor(a, 4);  a += __shfl_xor(a, 2); a += __shfl_xor(a, 1); \
    int kbase = ((pp) >> 2) * 7 + ((pp) & 3) * 2; \
    float v0 = __shfl(a, 0), v1 = __shfl(a, 32); \
    if (lane == kbase) mysim = v0; \
    if (((pp) & 3) < 3 && lane == kbase + 1) mysim = v1; }

  PLOAD(a0,a1,a2, 0);
  #pragma unroll
  for (int pp = 0; pp < 28; pp += 2){
    PLOAD(b0,b1,b2, pp + 1);
    __builtin_amdgcn_sched_barrier(0);
    PCOMP(a0,a1,a2, pp);
    if (pp + 2 < 28) PLOAD(a0,a1,a2, pp + 2);
    __builtin_amdgcn_sched_barrier(0);
    PCOMP(b0,b1,b2, pp + 1);
  }
#undef PLOAD
#undef PCOMP
  return mysim;
}

// ---------------- fast path: pixel-major layout ----------------

// Transpose [C, HW-tile] -> [pix, C], normalizing each pixel's channel vector.
// Round-1..3 proven version (fused read-once/write-once; traffic-optimal).
__global__ void tnorm_kernel(const float* __restrict__ src, float* __restrict__ dst){
  int blk = blockIdx.x;                 // B * (HW/TP)
  int b = blk / (HW / TP);
  int pixbase = (blk % (HW / TP)) * TP;
  __shared__ float tile[TP][CPAD];      // +1 pad: conflict-free col writes
  __shared__ float scale[TP];
  const float* sb = src + (size_t)b * C * HW + pixbase;
  int tx = threadIdx.x & 31;            // pixel in tile
  int ty = threadIdx.x >> 5;            // channel slice 0..7
  #pragma unroll 4
  for (int c0 = 0; c0 < C; c0 += 8){
    tile[tx][c0 + ty] = sb[(size_t)(c0 + ty) * HW + tx];
  }
  __syncthreads();
  // per-pixel sum of squares: 8 consecutive lanes per pixel
  int pix = threadIdx.x >> 3;
  int j = threadIdx.x & 7;
  float ss = 0.f;
  #pragma unroll 4
  for (int c = j * 48; c < j * 48 + 48; ++c){ float v = tile[pix][c]; ss = fmaf(v, v, ss); }
  ss += __shfl_xor(ss, 1); ss += __shfl_xor(ss, 2); ss += __shfl_xor(ss, 4);
  if (j == 0) scale[pix] = 1.0f / fmaxf(sqrtf(ss), 1e-12f);
  __syncthreads();
  float4* db4 = (float4*)(dst + ((size_t)b * HW + pixbase) * C);
  #pragma unroll 4
  for (int l = threadIdx.x; l < TP * (C / 4); l += 256){
    int p = l / (C / 4), c4 = l - p * (C / 4);
    float s = scale[p];
    float4 v;
    v.x = tile[p][c4 * 4 + 0] * s;
    v.y = tile[p][c4 * 4 + 1] * s;
    v.z = tile[p][c4 * 4 + 2] * s;
    v.w = tile[p][c4 * 4 + 3] * s;
    db4[(size_t)p * (C / 4) + c4] = v;
  }
}

// Spatial sort of the (image-shared) candidate list by 8x8 tile, ties by idx.
__global__ void sort_kernel(const int* __restrict__ anch, int* __restrict__ order){
  int i = blockIdx.x * 256 + threadIdx.x;    // 8 blocks x 256
  __shared__ int keys[M];
  for (int j = threadIdx.x; j < M; j += 256){
    int ay = anch[2 * j], ax = anch[2 * j + 1];
    keys[j] = (((ay >> 3) * 12 + (ax >> 3)) << 11) + j;
  }
  __syncthreads();
  int ki = keys[i];
  int r = 0;
  #pragma unroll 4
  for (int j = 0; j < M; ++j) r += (keys[j] < ki) ? 1 : 0;
  order[r] = i;
}

// 4 waves per block; one wave per (b, candidate). Spatially-sorted candidate
// order + bijective XCD chunk swizzle (R3: cut FETCH 1.05GB -> 0.25GB).
__global__ __launch_bounds__(256, 6) void cand2_kernel(const float* __restrict__ fT,
                             const int* __restrict__ anch, const int* __restrict__ order,
                             float* __restrict__ simc, float* __restrict__ ent){
  int nwg = B * M / 4;
  int bid = blockIdx.x;
  int swz = (bid & 7) * (nwg >> 3) + (bid >> 3);   // bijective, nwg%8==0
  int bm = swz * 4 + (threadIdx.x >> 6);
  int b = bm >> 11, mi = bm & (M - 1);
  int lane = threadIdx.x & 63;
  int m = order[mi];
  int ay = anch[2 * m], ax = anch[2 * m + 1];
  const float* img = fT + (size_t)b * HW * C;
  float mysim = patch_sims(img, ay, ax, lane) * INV_TAU;

  float v = (lane < K2) ? mysim : -INFINITY;
  float mx = wave_max(v);
  float e = (lane < K2) ? expf(mysim - mx) : 0.f;
  float se = wave_sum(e);
  float p = e / se;
  float term = (lane < K2) ? (-p * logf(p + 1e-6f)) : 0.f;
  float en = wave_sum(term);
  size_t slot = (size_t)b * M + m;
  if (lane == 0) ent[slot] = en;
  if (lane < K2) simc[slot * K2 + lane] = mysim;
}

// Exact top-512-smallest-entropy per image via lexicographic rank counting.
__global__ void select_kernel(const float* __restrict__ ent, int* __restrict__ sel){
  int blk = blockIdx.x;                 // B*8 blocks
  int b = blk >> 3;
  int i = (blk & 7) * 256 + threadIdx.x;
  __shared__ float se[M];
  for (int j = threadIdx.x; j < M; j += 256) se[j] = ent[b * M + j];
  __syncthreads();
  float ei = se[i];
  int r = 0;
  for (int j = 0; j < M; ++j){
    float ej = se[j];
    r += (ej < ei) || (ej == ei && j < i);
  }
  if (r < NSEL) sel[b * NSEL + r] = i;
}

// Spatially sort each image's 512 selected anchors for kl2 L2 locality.
// Packs (orig_pos << 11 | m): klpart slot keyed by orig_pos -> final sum
// order (and output bits) unchanged.
__global__ void selsort_kernel(const int* __restrict__ anch, const int* __restrict__ sel,
                               int* __restrict__ sel2){
  int b = blockIdx.x;                   // B blocks
  __shared__ int keys[NSEL];
  __shared__ int pos[NSEL];
  for (int j = threadIdx.x; j < NSEL; j += 256){
    int m = sel[b * NSEL + j];
    int ay = anch[2 * m], ax = anch[2 * m + 1];
    keys[j] = (((ay >> 3) * 12 + (ax >> 3)) << 11) | m;   // unique (m unique)
    pos[j] = j;
  }
  __syncthreads();
  for (int j = threadIdx.x; j < NSEL; j += 256){
    int kj = keys[j];
    int r = 0;
    #pragma unroll 4
    for (int i = 0; i < NSEL; ++i) r += (keys[i] < kj) ? 1 : 0;
    sel2[b * NSEL + r] = (pos[j] << 11) | (kj & (M - 1));
  }
}

// 4 waves per block; one wave per (b, sorted-selected anchor).
__global__ __launch_bounds__(256, 6) void kl2_kernel(const float* __restrict__ fS,
                           const int* __restrict__ anch,
                           const float* __restrict__ simc, const int* __restrict__ sel2,
                           float* __restrict__ klpart){
  int nwg = B * NSEL / 4;
  int bid = blockIdx.x;
  int swz = (bid & 7) * (nwg >> 3) + (bid >> 3);
  int bj = swz * 4 + (threadIdx.x >> 6);
  int b = bj >> 9, j = bj & (NSEL - 1);
  int lane = threadIdx.x & 63;
  int e2 = sel2[b * NSEL + j];
  int m = e2 & (M - 1), pos = e2 >> 11;
  int ay = anch[2 * m], ax = anch[2 * m + 1];
  const float* img = fS + (size_t)b * HW * C;
  float sim_sv = patch_sims(img, ay, ax, lane) * INV_TAU;
  float sim_tv = (lane < K2) ? simc[((size_t)b * M + m) * K2 + lane] : -INFINITY;

  float vs = (lane < K2) ? sim_sv : -INFINITY;
  float mxs = wave_max(vs);
  float es = (lane < K2) ? expf(sim_sv - mxs) : 0.f;
  float sums = wave_sum(es);
  float ls = sim_sv - mxs - logf(sums);

  float mxt = wave_max(sim_tv);
  float et = (lane < K2) ? expf(sim_tv - mxt) : 0.f;
  float sumt = wave_sum(et);
  float lt = sim_tv - mxt - logf(sumt);

  float pt = et / sumt;
  float term = (lane < K2) ? pt * (lt - ls) : 0.f;
  float kl = wave_sum(term);
  if (lane == 0) klpart[(b << 9) + pos] = kl;
}

__global__ void reduce_kernel(const float* __restrict__ part, float* __restrict__ out){
  float s = 0.f;
  for (int i = threadIdx.x; i < B * NSEL; i += 256) s += part[i];
  s = wave_sum(s);
  __shared__ float wsum[4];
  if ((threadIdx.x & 63) == 0) wsum[threadIdx.x >> 6] = s;
  __syncthreads();
  if (threadIdx.x == 0) out[0] = (wsum[0] + wsum[1] + wsum[2] + wsum[3]) * (1.0f / (B * NSEL));
}

// ---------------- fallback path (round-1, ~13 MB ws) ----------------

__global__ void norms_kernel(const float* __restrict__ t, const float* __restrict__ s,
                             float* __restrict__ inv_t, float* __restrict__ inv_s){
  int pix = blockIdx.x * blockDim.x + threadIdx.x;
  if (pix >= B * HW) return;
  int b = pix / HW, p = pix - b * HW;
  const float* tb = t + (size_t)b * C * HW + p;
  const float* sb = s + (size_t)b * C * HW + p;
  float at = 0.f, as = 0.f;
  #pragma unroll 4
  for (int c = 0; c < C; ++c){
    float v = tb[(size_t)c * HW]; at = fmaf(v, v, at);
    float u = sb[(size_t)c * HW]; as = fmaf(u, u, as);
  }
  inv_t[pix] = 1.0f / fmaxf(sqrtf(at), 1e-12f);
  inv_s[pix] = 1.0f / fmaxf(sqrtf(as), 1e-12f);
}

__global__ void cand_kernel(const float* __restrict__ t, const int* __restrict__ anch,
                            const float* __restrict__ inv_t,
                            float* __restrict__ simc, float* __restrict__ ent){
  int bm = blockIdx.x;
  int b = bm >> 11, m = bm & (M - 1);
  int lane = threadIdx.x;
  int ay = anch[2 * m], ax = anch[2 * m + 1];
  int k = lane < K2 ? lane : 0;
  int dy = k / 7 - RAD, dx = k - (k / 7) * 7 - RAD;
  int pc = ay * W + ax;
  int pk = (ay + dy) * W + (ax + dx);
  const float* base = t + (size_t)b * C * HW;
  float acc = 0.f;
  #pragma unroll 4
  for (int c = 0; c < C; ++c){
    const float* row = base + (size_t)c * HW;
    acc = fmaf(row[pc], row[pk], acc);
  }
  float sim = acc * inv_t[b * HW + pc] * inv_t[b * HW + pk] * INV_TAU;
  float v = (lane < K2) ? sim : -INFINITY;
  float mx = wave_max(v);
  float e = (lane < K2) ? expf(sim - mx) : 0.f;
  float se = wave_sum(e);
  float p = e / se;
  float term = (lane < K2) ? (-p * logf(p + 1e-6f)) : 0.f;
  float en = wave_sum(term);
  if (lane == 0) ent[bm] = en;
  if (lane < K2) simc[(size_t)bm * K2 + lane] = sim;
}

__global__ void kl_kernel(const float* __restrict__ s, const int* __restrict__ anch,
                          const float* __restrict__ inv_s, const float* __restrict__ simc,
                          const int* __restrict__ sel, float* __restrict__ klpart){
  int bj = blockIdx.x;
  int b = bj >> 9, j = bj & (NSEL - 1);
  int lane = threadIdx.x;
  int m = sel[b * NSEL + j];
  int ay = anch[2 * m], ax = anch[2 * m + 1];
  int k = lane < K2 ? lane : 0;
  int dy = k / 7 - RAD, dx = k - (k / 7) * 7 - RAD;
  int pc = ay * W + ax;
  int pk = (ay + dy) * W + (ax + dx);
  const float* base = s + (size_t)b * C * HW;
  float acc = 0.f;
  #pragma unroll 4
  for (int c = 0; c < C; ++c){
    const float* row = base + (size_t)c * HW;
    acc = fmaf(row[pc], row[pk], acc);
  }
  float sim_sv = acc * inv_s[b * HW + pc] * inv_s[b * HW + pk] * INV_TAU;
  float sim_tv = (lane < K2) ? simc[((size_t)b * M + m) * K2 + lane] : -INFINITY;

  float vs = (lane < K2) ? sim_sv : -INFINITY;
  float mxs = wave_max(vs);
  float es = (lane < K2) ? expf(sim_sv - mxs) : 0.f;
  float sums = wave_sum(es);
  float ls = sim_sv - mxs - logf(sums);

  float mxt = wave_max(sim_tv);
  float et = (lane < K2) ? expf(sim_tv - mxt) : 0.f;
  float sumt = wave_sum(et);
  float lt = sim_tv - mxt - logf(sumt);

  float pt = et / sumt;
  float term = (lane < K2) ? pt * (lt - ls) : 0.f;
  float kl = wave_sum(term);
  if (lane == 0) klpart[bj] = kl;
}

extern "C" void kernel_launch(void* const* d_in, const int* in_sizes, int n_in,
                              void* d_out, int out_size, void* d_ws, size_t ws_size,
                              hipStream_t stream){
  const float* student = (const float*)d_in[0];
  const float* teacher = (const float*)d_in[1];
  const int*   anch    = (const int*)d_in[2];
  float* out = (float*)d_out;

  const size_t fbuf_elems = (size_t)B * HW * C;            // 56.6M floats
  const size_t simc_elems = (size_t)B * M * K2;
  size_t req = (fbuf_elems + simc_elems + (size_t)B * M + (size_t)B * NSEL) * sizeof(float)
             + (2 * (size_t)B * NSEL + (size_t)M) * sizeof(int);

  if (ws_size >= req){
    float* fbuf   = (float*)d_ws;                          // reused: teacher then student
    float* simc   = fbuf + fbuf_elems;
    float* ent    = simc + simc_elems;
    float* klpart = ent + (size_t)B * M;
    int*   sel    = (int*)(klpart + (size_t)B * NSEL);
    int*   sel2   = sel + (size_t)B * NSEL;
    int*   order  = sel2 + (size_t)B * NSEL;

    hipLaunchKernelGGL(tnorm_kernel, dim3(B * (HW / TP)), dim3(256), 0, stream, teacher, fbuf);
    hipLaunchKernelGGL(sort_kernel, dim3(8), dim3(256), 0, stream, anch, order);
    hipLaunchKernelGGL(cand2_kernel, dim3(B * M / 4), dim3(256), 0, stream,
                       fbuf, anch, order, simc, ent);
    hipLaunchKernelGGL(select_kernel, dim3(B * 8), dim3(256), 0, stream, ent, sel);
    hipLaunchKernelGGL(selsort_kernel, dim3(B), dim3(256), 0, stream, anch, sel, sel2);
    hipLaunchKernelGGL(tnorm_kernel, dim3(B * (HW / TP)), dim3(256), 0, stream, student, fbuf);
    hipLaunchKernelGGL(kl2_kernel, dim3(B * NSEL / 4), dim3(256), 0, stream,
                       fbuf, anch, simc, sel2, klpart);
    hipLaunchKernelGGL(reduce_kernel, dim3(1), dim3(256), 0, stream, klpart, out);
  } else {
    float* ws2    = (float*)d_ws;
    float* inv_t  = ws2;
    float* inv_s  = inv_t + B * HW;
    float* ent    = inv_s + B * HW;
    float* simc   = ent + B * M;
    float* klpart = simc + simc_elems;
    int*   sel    = (int*)(klpart + (size_t)B * NSEL);

    hipLaunchKernelGGL(norms_kernel, dim3((B * HW + 255) / 256), dim3(256), 0, stream,
                       teacher, student, inv_t, inv_s);
    hipLaunchKernelGGL(cand_kernel, dim3(B * M), dim3(64), 0, stream,
                       teacher, anch, inv_t, simc, ent);
    hipLaunchKernelGGL(select_kernel, dim3(B * 8), dim3(256), 0, stream, ent, sel);
    hipLaunchKernelGGL(kl_kernel, dim3(B * NSEL), dim3(64), 0, stream,
                       student, anch, inv_s, simc, sel, klpart);
    hipLaunchKernelGGL(reduce_kernel, dim3(1), dim3(256), 0, stream, klpart, out);
  }
}